// Round 1
// baseline (131.999 us; speedup 1.0000x reference)
//
#include <hip/hip_runtime.h>
#include <hip/hip_bf16.h>

// Batched GEMM: out[bh][m][d] = sum_k x1[bh][m][k] * x2[bh][k][d]
// B*H = 32, S = 2048 (M and K), D = 64 (N). All fp32 in/out.
// Strategy: HBM-bound on x1 (537 MB). Cast to bf16, MFMA 16x16x32, fp32 acc.
//   - x1: direct global->reg->bf16 fragment (no LDS; each element used once).
//   - x2: staged per K-step (BK=128) into LDS transposed [d][k], +8 pad,
//         double-buffered; loads issued before compute, writes after (T14).
//   - Grid: 32 bh x 16 M-tiles (BM=128). 8 waves/block, each wave = 16 rows x 64 cols.

#define S_DIM 2048
#define D_DIM 64
#define BM 128
#define BK 128
#define NT (S_DIM / BK)   // 16 K-steps
#define LDB (BK + 8)      // 136 shorts per d-column: byte stride 272 (16B-aligned)

typedef __attribute__((ext_vector_type(8))) short short8;
typedef __attribute__((ext_vector_type(4))) short short4v;
typedef __attribute__((ext_vector_type(4))) float f32x4;

__device__ __forceinline__ short f2bf(float x) {
    return __builtin_bit_cast(short, __float2bfloat16(x));
}

__global__ __launch_bounds__(512, 2)
void pv_gemm_kernel(const float* __restrict__ x1,
                    const float* __restrict__ x2,
                    float* __restrict__ out) {
    __shared__ short lds_b[2][D_DIM][LDB];   // 34,816 bytes

    // XCD-aware bijective swizzle (512 % 8 == 0): each XCD gets 64 consecutive
    // logical tiles = 4 bh's worth of x2 (2 MB) -> fits 4 MB per-XCD L2.
    int bid = blockIdx.x;
    int lb  = (bid & 7) * 64 + (bid >> 3);
    int bh   = lb >> 4;       // 0..31
    int mblk = lb & 15;       // 0..15
    int m0   = mblk * BM;

    int tid  = threadIdx.x;
    int lane = tid & 63;
    int w    = tid >> 6;      // wave 0..7

    // ---- x2 staging coords: thread t loads column d = t&63, k-block t>>6 (16 k's)
    int sd  = tid & 63;
    int skb = tid >> 6;
    const float* x2base = x2 + (size_t)bh * S_DIM * D_DIM + sd;

    // ---- A fragment coords (mfma 16x16x32 bf16: row = lane&15, k = (lane>>4)*8 + j)
    int arow = m0 + w * 16 + (lane & 15);
    int kgrp = (lane >> 4) * 8;
    const float* abase = x1 + ((size_t)bh * S_DIM + arow) * S_DIM + kgrp;

    f32x4 acc[4];
#pragma unroll
    for (int i = 0; i < 4; ++i) acc[i] = (f32x4){0.f, 0.f, 0.f, 0.f};

    // ---- prologue: stage K-tile 0 into buffer 0
    {
        float rs[16];
#pragma unroll
        for (int i = 0; i < 16; ++i)
            rs[i] = x2base[(size_t)(skb * 16 + i) * D_DIM];
#pragma unroll
        for (int j = 0; j < 4; ++j) {
            short4v v;
            v[0] = f2bf(rs[4 * j + 0]);
            v[1] = f2bf(rs[4 * j + 1]);
            v[2] = f2bf(rs[4 * j + 2]);
            v[3] = f2bf(rs[4 * j + 3]);
            *(short4v*)&lds_b[0][sd][skb * 16 + 4 * j] = v;
        }
    }

    int buf = 0;
    for (int t = 0; t < NT; ++t) {
        __syncthreads();   // stage[t] writes visible; prev reads of buf^1 done

        // issue next K-tile's global loads early (hide HBM latency under MFMA)
        float rn[16];
        if (t + 1 < NT) {
            const float* p = x2base + (size_t)(t + 1) * BK * D_DIM;
#pragma unroll
            for (int i = 0; i < 16; ++i)
                rn[i] = p[(size_t)(skb * 16 + i) * D_DIM];
        }

        // ---- compute on lds_b[buf]
        const float* ab = abase + (size_t)t * BK;
#pragma unroll
        for (int kk = 0; kk < 4; ++kk) {
            float4 lo = *(const float4*)(ab + kk * 32);
            float4 hi = *(const float4*)(ab + kk * 32 + 4);
            short8 a;
            a[0] = f2bf(lo.x); a[1] = f2bf(lo.y); a[2] = f2bf(lo.z); a[3] = f2bf(lo.w);
            a[4] = f2bf(hi.x); a[5] = f2bf(hi.y); a[6] = f2bf(hi.z); a[7] = f2bf(hi.w);
#pragma unroll
            for (int ni = 0; ni < 4; ++ni) {
                int col = ni * 16 + (lane & 15);
                const short8* bp =
                    (const short8*)&lds_b[buf][col][kk * 32 + kgrp];
                acc[ni] = __builtin_amdgcn_mfma_f32_16x16x32_bf16(a, *bp, acc[ni], 0, 0, 0);
            }
        }

        // write staged tile t+1 into the other buffer
        if (t + 1 < NT) {
#pragma unroll
            for (int j = 0; j < 4; ++j) {
                short4v v;
                v[0] = f2bf(rn[4 * j + 0]);
                v[1] = f2bf(rn[4 * j + 1]);
                v[2] = f2bf(rn[4 * j + 2]);
                v[3] = f2bf(rn[4 * j + 3]);
                *(short4v*)&lds_b[buf ^ 1][sd][skb * 16 + 4 * j] = v;
            }
        }
        buf ^= 1;
    }

    // ---- epilogue: C/D layout col = lane&15, row = (lane>>4)*4 + reg
    int col0 = lane & 15;
    int r0   = m0 + w * 16 + ((lane >> 4) << 2);
    float* ob = out + ((size_t)bh * S_DIM + r0) * D_DIM + col0;
#pragma unroll
    for (int ni = 0; ni < 4; ++ni) {
#pragma unroll
        for (int r = 0; r < 4; ++r)
            ob[(size_t)r * D_DIM + ni * 16] = acc[ni][r];
    }
}

extern "C" void kernel_launch(void* const* d_in, const int* in_sizes, int n_in,
                              void* d_out, int out_size, void* d_ws, size_t ws_size,
                              hipStream_t stream) {
    const float* x1 = (const float*)d_in[0];   // [2,16,2048,2048] softmax probs
    const float* x2 = (const float*)d_in[1];   // [2,16,2048,64]
    float* out = (float*)d_out;                // [2,16,2048,64]

    dim3 grid(512);   // 32 bh * 16 M-tiles
    dim3 block(512);  // 8 waves
    hipLaunchKernelGGL(pv_gemm_kernel, grid, block, 0, stream, x1, x2, out);
}

// Round 2
// 116.760 us; speedup vs baseline: 1.1305x; 1.1305x over previous
//
#include <hip/hip_runtime.h>
#include <hip/hip_bf16.h>

// Batched GEMM: out[bh][m][d] = sum_k x1[bh][m][k] * x2[bh][k][d]
// B*H = 32, S = 2048 (M and K), D = 64 (N). All fp32 in/out.
// HBM-bound on x1 (537 MB, zero reuse). bf16 MFMA 16x16x32, fp32 acc.
// R1 changes vs R0:
//   - depth-1 register prefetch of next A-tile (issue post-barrier, use next step)
//   - manual unroll-by-2 for static ping-pong register sets (no scratch)
//   - x2 reg-loads issued BEFORE A-loads (ds_write's counted vmcnt leaves A in flight)
//   - __launch_bounds__(512,4): force VGPR<=128 -> 2 blocks/CU guaranteed

#define S_DIM 2048
#define D_DIM 64
#define BM 128
#define BK 128
#define NT (S_DIM / BK)   // 16 K-steps
#define LDB (BK + 8)      // byte stride 272: 16B-aligned, 2-way bank pattern (free)

typedef __attribute__((ext_vector_type(8))) short short8;
typedef __attribute__((ext_vector_type(4))) short short4v;
typedef __attribute__((ext_vector_type(4))) float f32x4;

__device__ __forceinline__ short f2bf(float x) {
    return __builtin_bit_cast(short, __float2bfloat16(x));
}

__global__ __launch_bounds__(512, 4)
void pv_gemm_kernel(const float* __restrict__ x1,
                    const float* __restrict__ x2,
                    float* __restrict__ out) {
    __shared__ short lds_b[2][D_DIM][LDB];   // 34,816 bytes

    // XCD-aware bijective swizzle (512 % 8 == 0)
    int bid = blockIdx.x;
    int lb  = (bid & 7) * 64 + (bid >> 3);
    int bh   = lb >> 4;
    int mblk = lb & 15;
    int m0   = mblk * BM;

    int tid  = threadIdx.x;
    int lane = tid & 63;
    int w    = tid >> 6;

    // x2 staging coords: thread t loads column d = t&63, k-block t>>6
    int sd  = tid & 63;
    int skb = tid >> 6;
    const float* x2base = x2 + (size_t)bh * S_DIM * D_DIM + sd;

    // A fragment coords (mfma 16x16x32 bf16: row = lane&15, k = (lane>>4)*8 + j)
    int arow = m0 + w * 16 + (lane & 15);
    int kgrp = (lane >> 4) * 8;
    const float* abase = x1 + ((size_t)bh * S_DIM + arow) * S_DIM + kgrp;

    f32x4 acc[4];
#pragma unroll
    for (int i = 0; i < 4; ++i) acc[i] = (f32x4){0.f, 0.f, 0.f, 0.f};

    // ---- prologue: stage x2 tile 0 into LDS buffer 0
    {
        float rs[16];
#pragma unroll
        for (int i = 0; i < 16; ++i)
            rs[i] = x2base[(size_t)(skb * 16 + i) * D_DIM];
#pragma unroll
        for (int j = 0; j < 4; ++j) {
            short4v v;
            v[0] = f2bf(rs[4 * j + 0]);
            v[1] = f2bf(rs[4 * j + 1]);
            v[2] = f2bf(rs[4 * j + 2]);
            v[3] = f2bf(rs[4 * j + 3]);
            *(short4v*)&lds_b[0][sd][skb * 16 + 4 * j] = v;
        }
    }

    // ---- prologue: load A tile 0 into rA0
    float4 rA0[8], rA1[8];
#pragma unroll
    for (int kk = 0; kk < 4; ++kk) {
        rA0[2 * kk]     = *(const float4*)(abase + kk * 32);
        rA0[2 * kk + 1] = *(const float4*)(abase + kk * 32 + 4);
    }

// One K-step. RBUF: static LDS read-buffer index. RA_CUR: A regs for this
// step (already loaded). RA_NXT: A regs filled for the next step.
#define ITER(T, RBUF, RA_CUR, RA_NXT)                                        \
    {                                                                        \
        __syncthreads();                                                     \
        float rn[16];                                                        \
        if ((T) + 1 < NT) {                                                  \
            /* x2 loads FIRST (older in vmcnt FIFO than A loads) */          \
            const float* p = x2base + (size_t)((T) + 1) * BK * D_DIM;        \
            _Pragma("unroll")                                                \
            for (int i = 0; i < 16; ++i)                                     \
                rn[i] = p[(size_t)(skb * 16 + i) * D_DIM];                   \
            const float* an = abase + (size_t)((T) + 1) * BK;                \
            _Pragma("unroll")                                                \
            for (int kk = 0; kk < 4; ++kk) {                                 \
                RA_NXT[2 * kk]     = *(const float4*)(an + kk * 32);         \
                RA_NXT[2 * kk + 1] = *(const float4*)(an + kk * 32 + 4);     \
            }                                                                \
        }                                                                    \
        _Pragma("unroll")                                                    \
        for (int kk = 0; kk < 4; ++kk) {                                     \
            short8 a;                                                        \
            a[0] = f2bf(RA_CUR[2 * kk].x);                                   \
            a[1] = f2bf(RA_CUR[2 * kk].y);                                   \
            a[2] = f2bf(RA_CUR[2 * kk].z);                                   \
            a[3] = f2bf(RA_CUR[2 * kk].w);                                   \
            a[4] = f2bf(RA_CUR[2 * kk + 1].x);                               \
            a[5] = f2bf(RA_CUR[2 * kk + 1].y);                               \
            a[6] = f2bf(RA_CUR[2 * kk + 1].z);                               \
            a[7] = f2bf(RA_CUR[2 * kk + 1].w);                               \
            _Pragma("unroll")                                                \
            for (int ni = 0; ni < 4; ++ni) {                                 \
                const short8* bp = (const short8*)                           \
                    &lds_b[RBUF][ni * 16 + (lane & 15)][kk * 32 + kgrp];     \
                acc[ni] = __builtin_amdgcn_mfma_f32_16x16x32_bf16(           \
                    a, *bp, acc[ni], 0, 0, 0);                               \
            }                                                                \
        }                                                                    \
        if ((T) + 1 < NT) {                                                  \
            _Pragma("unroll")                                                \
            for (int j = 0; j < 4; ++j) {                                    \
                short4v v;                                                   \
                v[0] = f2bf(rn[4 * j + 0]);                                  \
                v[1] = f2bf(rn[4 * j + 1]);                                  \
                v[2] = f2bf(rn[4 * j + 2]);                                  \
                v[3] = f2bf(rn[4 * j + 3]);                                  \
                *(short4v*)&lds_b[(RBUF) ^ 1][sd][skb * 16 + 4 * j] = v;     \
            }                                                                \
        }                                                                    \
    }

    for (int t = 0; t < NT; t += 2) {
        ITER(t,     0, rA0, rA1);
        ITER(t + 1, 1, rA1, rA0);
    }
#undef ITER

    // ---- epilogue: C/D layout col = lane&15, row = (lane>>4)*4 + reg
    int col0 = lane & 15;
    int r0   = m0 + w * 16 + ((lane >> 4) << 2);
    float* ob = out + ((size_t)bh * S_DIM + r0) * D_DIM + col0;
#pragma unroll
    for (int ni = 0; ni < 4; ++ni) {
#pragma unroll
        for (int r = 0; r < 4; ++r)
            ob[(size_t)r * D_DIM + ni * 16] = acc[ni][r];
    }
}

extern "C" void kernel_launch(void* const* d_in, const int* in_sizes, int n_in,
                              void* d_out, int out_size, void* d_ws, size_t ws_size,
                              hipStream_t stream) {
    const float* x1 = (const float*)d_in[0];   // [2,16,2048,2048] softmax probs
    const float* x2 = (const float*)d_in[1];   // [2,16,2048,64]
    float* out = (float*)d_out;                // [2,16,2048,64]

    dim3 grid(512);   // 32 bh * 16 M-tiles
    dim3 block(512);  // 8 waves
    hipLaunchKernelGGL(pv_gemm_kernel, grid, block, 0, stream, x1, x2, out);
}